// Round 12
// baseline (1162.033 us; speedup 1.0000x reference)
//
#include <hip/hip_runtime.h>
#include <hip/hip_bf16.h>
#include <hip/hip_cooperative_groups.h>

#define SEQ 256
#define IND 4096
#define HID 2048
#define NCLS 10
#define NBLK 256
#define CCOLS 32          // cols per worker block
#define NWORK 64          // worker blocks (2 XCDs x 32)

// ---------------------------------------------------------------------------
// Kernel 1: xw = x @ W_hx (M=256,K=4096,N=2048 f32). Known-good, untouched.
// ---------------------------------------------------------------------------
__global__ __launch_bounds__(256) void xw_gemm3(const float* __restrict__ A,
                                                const float* __restrict__ B,
                                                float* __restrict__ C) {
    __shared__ float As[32][68];
    __shared__ float Bs[64][64];
    const int bm = blockIdx.y * 32;
    const int bn = blockIdx.x * 64;
    const int tid = threadIdx.x;
    const int tx = tid & 15;
    const int ty = tid >> 4;

    float acc[2][4] = {};

    for (int k0 = 0; k0 < IND; k0 += 64) {
        {
            const int ar = tid >> 3;
            const int kq = (tid & 7) * 8;
            const float4 a0 = *reinterpret_cast<const float4*>(
                &A[(size_t)(bm + ar) * IND + k0 + kq]);
            const float4 a1 = *reinterpret_cast<const float4*>(
                &A[(size_t)(bm + ar) * IND + k0 + kq + 4]);
            *reinterpret_cast<float4*>(&As[ar][kq]) = a0;
            *reinterpret_cast<float4*>(&As[ar][kq + 4]) = a1;
        }
        {
            const int cq = (tid & 15) * 4;
            #pragma unroll
            for (int j = 0; j < 4; ++j) {
                const int kr = (tid >> 4) + j * 16;
                *reinterpret_cast<float4*>(&Bs[kr][cq]) =
                    *reinterpret_cast<const float4*>(
                        &B[(size_t)(k0 + kr) * HID + bn + cq]);
            }
        }
        __syncthreads();

        #pragma unroll
        for (int k4 = 0; k4 < 64; k4 += 4) {
            const float4 a0 = *reinterpret_cast<const float4*>(&As[ty * 2 + 0][k4]);
            const float4 a1 = *reinterpret_cast<const float4*>(&As[ty * 2 + 1][k4]);
            const float4 b0 = *reinterpret_cast<const float4*>(&Bs[k4 + 0][tx * 4]);
            const float4 b1 = *reinterpret_cast<const float4*>(&Bs[k4 + 1][tx * 4]);
            const float4 b2 = *reinterpret_cast<const float4*>(&Bs[k4 + 2][tx * 4]);
            const float4 b3 = *reinterpret_cast<const float4*>(&Bs[k4 + 3][tx * 4]);
            acc[0][0] += a0.x*b0.x + a0.y*b1.x + a0.z*b2.x + a0.w*b3.x;
            acc[0][1] += a0.x*b0.y + a0.y*b1.y + a0.z*b2.y + a0.w*b3.y;
            acc[0][2] += a0.x*b0.z + a0.y*b1.z + a0.z*b2.z + a0.w*b3.z;
            acc[0][3] += a0.x*b0.w + a0.y*b1.w + a0.z*b2.w + a0.w*b3.w;
            acc[1][0] += a1.x*b0.x + a1.y*b1.x + a1.z*b2.x + a1.w*b3.x;
            acc[1][1] += a1.x*b0.y + a1.y*b1.y + a1.z*b2.y + a1.w*b3.y;
            acc[1][2] += a1.x*b0.z + a1.y*b1.z + a1.z*b2.z + a1.w*b3.z;
            acc[1][3] += a1.x*b0.w + a1.y*b1.w + a1.z*b2.w + a1.w*b3.w;
        }
        __syncthreads();
    }

    #pragma unroll
    for (int i = 0; i < 2; ++i) {
        float4 cv = make_float4(acc[i][0], acc[i][1], acc[i][2], acc[i][3]);
        *reinterpret_cast<float4*>(
            &C[(size_t)(bm + ty * 2 + i) * HID + bn + tx * 4]) = cv;
    }
}

// f32 -> bf16 bits (round to nearest even)
__device__ __forceinline__ unsigned f2bf(float f) {
    unsigned u = __float_as_uint(f);
    u += 0x7fffu + ((u >> 16) & 1u);
    return u >> 16;
}
__device__ __forceinline__ float bflo(unsigned u) { return __uint_as_float(u << 16); }
__device__ __forceinline__ float bfhi(unsigned u) { return __uint_as_float(u & 0xffff0000u); }

// ---------------------------------------------------------------------------
// Kernel 2 (rnn_v10): 2-XCD-concentrated tagged-dataflow RNN.
// Coop launch 256 blocks; each reads HW_REG_XCC_ID (HW-verified m09) and
// takes a per-XCD ticket. Blocks on XCD 0/1 with ticket<32 become the 64
// workers (32 cols each: chunk = xcc*32 + slot); everyone else exits.
// Coverage guaranteed: 144KB LDS => 1 block/CU => exactly 32 blocks/XCD.
// Per step per worker:
//   prefetch xw -> detect tag t over all 2048 packed words (8/thread,
//   got-mask re-poll) staging into parity v2 -> ONE barrier -> GEMV:
//   thread (s=t&63,q=t>>6) does rows s*32..+32 x cols q*8..+8 from bf16 W
//   in LDS (row-sliced uint4 = 8 cols, swizzled i^(tslot&7); v2 quads
//   swizzled i4^(s&7); <=2-way banks verified per quarter-wave) -> 6-stage
//   shfl butterfly over s -> lanes 0..7 of each wave add xw+bias, tanh,
//   publish 8 tagged words (64B line per wave).
// Safety: parity-double v2 + one barrier (publish(t+2) transitively
// follows every reader's GEMV(t) completion via two consumer hops —
// argument re-verified); stale tags from prior replays carry identical
// deterministic values; 0xAA never matches a tag. Election order varies
// across replays but chunk->values mapping is deterministic.
// ---------------------------------------------------------------------------
__global__ __launch_bounds__(256, 1) void rnn_v10(const float* __restrict__ W,
                                                  const float* __restrict__ xwg,
                                                  const float* __restrict__ b_h,
                                                  unsigned long long* __restrict__ buf,
                                                  unsigned* __restrict__ tick) {
    const int tid = threadIdx.x;

    __shared__ int schunk;
    if (tid == 0) {
        unsigned xcc;
        asm volatile("s_getreg_b32 %0, hwreg(HW_REG_XCC_ID)" : "=s"(xcc));
        xcc &= 7u;
        const unsigned slot = __hip_atomic_fetch_add(&tick[xcc], 1u,
                                                     __ATOMIC_RELAXED,
                                                     __HIP_MEMORY_SCOPE_AGENT);
        schunk = (xcc < 2 && slot < 32) ? (int)(xcc * 32 + slot) : -1;
    }
    __syncthreads();
    const int chunk = schunk;
    if (chunk < 0) return;
    const int c0 = chunk * CCOLS;

    __shared__ uint4 Wl4[256 * 32];     // 128 KiB bf16 W slice
    __shared__ float v2[2][HID];        // 16 KiB parity double-buffer

    // ---- stage W slice: uint4 = one row x 8 cols, swizzled (once)
    for (int j = 0; j < 32; ++j) {
        const int idx = j * 256 + tid;          // 0..8191
        const int q = idx & 3, r = idx >> 2;
        const float4 a = *reinterpret_cast<const float4*>(
            &W[(size_t)r * HID + c0 + q * 8]);
        const float4 b = *reinterpret_cast<const float4*>(
            &W[(size_t)r * HID + c0 + q * 8 + 4]);
        uint4 pk;
        pk.x = f2bf(a.x) | (f2bf(a.y) << 16);
        pk.y = f2bf(a.z) | (f2bf(a.w) << 16);
        pk.z = f2bf(b.x) | (f2bf(b.y) << 16);
        pk.w = f2bf(b.z) | (f2bf(b.w) << 16);
        const int s = r >> 5, i = r & 31;
        const int tslot = q * 64 + s;
        Wl4[tslot * 32 + (i ^ (tslot & 7))] = pk;
    }
    for (int i = tid; i < HID; i += 256) v2[0][i] = 0.0f;

    const int lane = tid & 63;               // = s (row-span)
    const int q = tid >> 6;                  // wave = col-group
    const int s = lane;
    const int tslot = q * 64 + s;
    const float bias = (lane < 8) ? b_h[c0 + q * 8 + lane] : 0.0f;
    __syncthreads();

    for (int t = 0; t < SEQ; ++t) {
        const int par = t & 1;
        // prefetch this step's xw (L2-resident; used after GEMV)
        float xwv = 0.0f;
        if (lane < 8) xwv = xwg[(size_t)t * HID + c0 + q * 8 + lane];

        // ---- detect tag t over all 2048 packed words; stage into v2[par]
        if (t > 0) {
            const unsigned long long* bb = buf + (size_t)par * HID;
            const unsigned tg = (unsigned)t;
            unsigned long long w[8];
            unsigned got = 0;
            #pragma unroll
            for (int k = 0; k < 8; ++k)
                w[k] = __hip_atomic_load(&bb[k * 256 + tid], __ATOMIC_RELAXED,
                                         __HIP_MEMORY_SCOPE_AGENT);
            for (;;) {
                #pragma unroll
                for (int k = 0; k < 8; ++k) {
                    if (!(got & (1u << k)) && (unsigned)(w[k] >> 32) == tg) {
                        const int r = k * 256 + tid;
                        const int qL = r >> 2;
                        const int phys = (qL & ~7) | ((qL & 7) ^ ((r >> 5) & 7));
                        v2[par][phys * 4 + (r & 3)] = __uint_as_float((unsigned)w[k]);
                        got |= (1u << k);
                    }
                }
                if (got == 0xFFu) break;
                #pragma unroll
                for (int k = 0; k < 8; ++k)
                    if (!(got & (1u << k)))
                        w[k] = __hip_atomic_load(&bb[k * 256 + tid],
                                                 __ATOMIC_RELAXED,
                                                 __HIP_MEMORY_SCOPE_AGENT);
            }
        }
        __syncthreads();   // the ONE per-step barrier

        // ---- GEMV: rows s*32..+32, cols q*8..+8
        float acc[8] = {};
        #pragma unroll
        for (int i4 = 0; i4 < 8; ++i4) {
            const float4 vv = *reinterpret_cast<const float4*>(
                &v2[par][((s * 8) | (i4 ^ (s & 7))) * 4]);
            #pragma unroll
            for (int e = 0; e < 4; ++e) {
                const int i = i4 * 4 + e;
                const uint4 wq = Wl4[tslot * 32 + (i ^ (tslot & 7))];
                const float vk = (e == 0) ? vv.x : (e == 1) ? vv.y
                                : (e == 2) ? vv.z : vv.w;
                acc[0] += vk * bflo(wq.x); acc[1] += vk * bfhi(wq.x);
                acc[2] += vk * bflo(wq.y); acc[3] += vk * bfhi(wq.y);
                acc[4] += vk * bflo(wq.z); acc[5] += vk * bfhi(wq.z);
                acc[6] += vk * bflo(wq.w); acc[7] += vk * bfhi(wq.w);
            }
        }
        // ---- butterfly over the 64 row-span lanes
        #pragma unroll
        for (int st = 1; st <= 32; st <<= 1) {
            #pragma unroll
            for (int c = 0; c < 8; ++c)
                acc[c] += __shfl_xor(acc[c], st, 64);
        }

        // ---- lanes 0..7 finish + publish (one 64B line per wave)
        if (lane < 8) {
            float mine = acc[0];
            #pragma unroll
            for (int c = 1; c < 8; ++c) mine = (lane == c) ? acc[c] : mine;
            const float h = tanhf(mine + xwv + bias);
            const unsigned long long pk =
                ((unsigned long long)(unsigned)(t + 1) << 32) |
                (unsigned long long)__float_as_uint(h);
            __hip_atomic_store(&buf[(size_t)((t + 1) & 1) * HID + c0 + q * 8 + lane],
                               pk, __ATOMIC_RELAXED, __HIP_MEMORY_SCOPE_AGENT);
        }
    }
}

// ---------------------------------------------------------------------------
// Kernel 3: out = softmax(2048 * (v @ W_ph + b_p)); v = tag-256 values in
// buf parity 0 (stream-ordered after rnn_v10 -> plain reads).
// ---------------------------------------------------------------------------
__global__ __launch_bounds__(256) void final_v3(const unsigned long long* __restrict__ buf,
                                                const float* __restrict__ W_ph,
                                                const float* __restrict__ b_p,
                                                float* __restrict__ out) {
    __shared__ float red[256][NCLS];
    const int tid = threadIdx.x;
    float acc[NCLS] = {};
    for (int k = 0; k < 8; ++k) {
        const int r = k * 256 + tid;
        const float v = __uint_as_float((unsigned)buf[r]);   // parity 0
        #pragma unroll
        for (int c = 0; c < NCLS; ++c)
            acc[c] += v * W_ph[(size_t)r * NCLS + c];
    }
    #pragma unroll
    for (int c = 0; c < NCLS; ++c) red[tid][c] = acc[c];
    __syncthreads();
    for (int sft = 128; sft > 0; sft >>= 1) {
        if (tid < sft) {
            #pragma unroll
            for (int c = 0; c < NCLS; ++c)
                red[tid][c] += red[tid + sft][c];
        }
        __syncthreads();
    }
    if (tid == 0) {
        float logits[NCLS];
        float m = -1e30f;
        #pragma unroll
        for (int c = 0; c < NCLS; ++c) {
            logits[c] = (float)HID * (red[0][c] + b_p[c]);
            m = fmaxf(m, logits[c]);
        }
        float den = 0.0f, e[NCLS];
        #pragma unroll
        for (int c = 0; c < NCLS; ++c) {
            e[c] = expf(logits[c] - m);
            den += e[c];
        }
        #pragma unroll
        for (int c = 0; c < NCLS; ++c) out[c] = e[c] / den;
    }
}

// ---------------------------------------------------------------------------
extern "C" void kernel_launch(void* const* d_in, const int* in_sizes, int n_in,
                              void* d_out, int out_size, void* d_ws, size_t ws_size,
                              hipStream_t stream) {
    const float* x    = (const float*)d_in[0];
    const float* W_hx = (const float*)d_in[1];
    const float* W_hh = (const float*)d_in[2];
    const float* W_ph = (const float*)d_in[3];
    const float* b_h  = (const float*)d_in[4];
    const float* b_p  = (const float*)d_in[5];
    float* out = (float*)d_out;

    float* xw               = (float*)d_ws;                                  // 2 MB
    unsigned long long* buf = (unsigned long long*)(xw + (size_t)SEQ * HID); // 32 KB
    unsigned* tick          = (unsigned*)(buf + 2 * HID);                    // 32 B

    // per-XCD ticket counters must start at 0 (also on every graph replay)
    hipMemsetAsync(tick, 0, 8 * sizeof(unsigned), stream);

    // 1) xw = x @ W_hx
    dim3 g1(HID / 64, SEQ / 32);
    xw_gemm3<<<g1, 256, 0, stream>>>(x, W_hx, xw);

    // 2) recurrent steps (cooperative; 64 workers on XCDs 0-1)
    {
        const float* whh_a = W_hh;
        const float* xw_a  = xw;
        const float* bh_a  = b_h;
        unsigned long long* buf_a = buf;
        unsigned* tick_a = tick;
        void* args[] = {(void*)&whh_a, (void*)&xw_a, (void*)&bh_a,
                        (void*)&buf_a, (void*)&tick_a};
        hipLaunchCooperativeKernel((const void*)rnn_v10, dim3(NBLK), dim3(256),
                                   args, 0, stream);
    }

    // 3) projection + softmax
    final_v3<<<1, 256, 0, stream>>>(buf, W_ph, b_p, out);
}

// Round 13
// 833.358 us; speedup vs baseline: 1.3944x; 1.3944x over previous
//
#include <hip/hip_runtime.h>
#include <hip/hip_bf16.h>
#include <hip/hip_cooperative_groups.h>

#define SEQ 256
#define IND 4096
#define HID 2048
#define NCLS 10
#define NBLK 256
#define COLS 8
#define VST 8   // u64 stride per producer line (64 B: 4 used + 4 pad)

// ---------------------------------------------------------------------------
// Kernel 1: xw = x @ W_hx (M=256,K=4096,N=2048 f32). Known-good, untouched.
// ---------------------------------------------------------------------------
__global__ __launch_bounds__(256) void xw_gemm3(const float* __restrict__ A,
                                                const float* __restrict__ B,
                                                float* __restrict__ C) {
    __shared__ float As[32][68];
    __shared__ float Bs[64][64];
    const int bm = blockIdx.y * 32;
    const int bn = blockIdx.x * 64;
    const int tid = threadIdx.x;
    const int tx = tid & 15;
    const int ty = tid >> 4;

    float acc[2][4] = {};

    for (int k0 = 0; k0 < IND; k0 += 64) {
        {
            const int ar = tid >> 3;
            const int kq = (tid & 7) * 8;
            const float4 a0 = *reinterpret_cast<const float4*>(
                &A[(size_t)(bm + ar) * IND + k0 + kq]);
            const float4 a1 = *reinterpret_cast<const float4*>(
                &A[(size_t)(bm + ar) * IND + k0 + kq + 4]);
            *reinterpret_cast<float4*>(&As[ar][kq]) = a0;
            *reinterpret_cast<float4*>(&As[ar][kq + 4]) = a1;
        }
        {
            const int cq = (tid & 15) * 4;
            #pragma unroll
            for (int j = 0; j < 4; ++j) {
                const int kr = (tid >> 4) + j * 16;
                *reinterpret_cast<float4*>(&Bs[kr][cq]) =
                    *reinterpret_cast<const float4*>(
                        &B[(size_t)(k0 + kr) * HID + bn + cq]);
            }
        }
        __syncthreads();

        #pragma unroll
        for (int k4 = 0; k4 < 64; k4 += 4) {
            const float4 a0 = *reinterpret_cast<const float4*>(&As[ty * 2 + 0][k4]);
            const float4 a1 = *reinterpret_cast<const float4*>(&As[ty * 2 + 1][k4]);
            const float4 b0 = *reinterpret_cast<const float4*>(&Bs[k4 + 0][tx * 4]);
            const float4 b1 = *reinterpret_cast<const float4*>(&Bs[k4 + 1][tx * 4]);
            const float4 b2 = *reinterpret_cast<const float4*>(&Bs[k4 + 2][tx * 4]);
            const float4 b3 = *reinterpret_cast<const float4*>(&Bs[k4 + 3][tx * 4]);
            acc[0][0] += a0.x*b0.x + a0.y*b1.x + a0.z*b2.x + a0.w*b3.x;
            acc[0][1] += a0.x*b0.y + a0.y*b1.y + a0.z*b2.y + a0.w*b3.y;
            acc[0][2] += a0.x*b0.z + a0.y*b1.z + a0.z*b2.z + a0.w*b3.z;
            acc[0][3] += a0.x*b0.w + a0.y*b1.w + a0.z*b2.w + a0.w*b3.w;
            acc[1][0] += a1.x*b0.x + a1.y*b1.x + a1.z*b2.x + a1.w*b3.x;
            acc[1][1] += a1.x*b0.y + a1.y*b1.y + a1.z*b2.y + a1.w*b3.y;
            acc[1][2] += a1.x*b0.z + a1.y*b1.z + a1.z*b2.z + a1.w*b3.z;
            acc[1][3] += a1.x*b0.w + a1.y*b1.w + a1.z*b2.w + a1.w*b3.w;
        }
        __syncthreads();
    }

    #pragma unroll
    for (int i = 0; i < 2; ++i) {
        float4 cv = make_float4(acc[i][0], acc[i][1], acc[i][2], acc[i][3]);
        *reinterpret_cast<float4*>(
            &C[(size_t)(bm + ty * 2 + i) * HID + bn + tx * 4]) = cv;
    }
}

// f32 -> bf16 bits (round to nearest even)
__device__ __forceinline__ unsigned f2bf(float f) {
    unsigned u = __float_as_uint(f);
    u += 0x7fffu + ((u >> 16) & 1u);
    return u >> 16;
}
__device__ __forceinline__ float bflo(unsigned u) { return __uint_as_float(u << 16); }
__device__ __forceinline__ float bfhi(unsigned u) { return __uint_as_float(u & 0xffff0000u); }

// ---------------------------------------------------------------------------
// Kernel 2 (rnn_v11): tagged-dataflow RNN, step-indexed publish buffer,
// one-producer-per-thread gated detect, bf16-packed values.
// 256 blocks x 256 thr; block b owns output cols [b*8, b*8+8).
// Publish: wave 0 of block b writes 4 self-tagged u64 words
//   word j = (t+1)<<32 | bf16(h[2j]) | bf16(h[2j+1])<<16
// on the 64B-aligned line vtag[(t+1)*2048 + b*8 ...]. Step-indexed address
// => fresh line per step (no parity reuse); vtag is memset(0) in-graph each
// launch => no cross-replay coasting; tag 0 / 0xAA never matches t>=1.
// Detect: thread tid gates on word 0 of producer tid's line (ONE atomic
// load per sweep, 8x fewer MALL ops than the all-rows sweep), then reads
// words 1..3 with per-word tag verify (self-tagged => no fences/ordering
// assumptions anywhere). Thread tid stages rows tid*8..+8 = its own wave's
// GEMV quarter => wave-autonomous, no barrier between stage and GEMV
// (wave-lockstep + lgkmcnt orders ds_write before ds_read).
// GEMV/LDS layouts copied verbatim from v6 (measured 3.9e5 conflicts):
// bf16 W in Wfb (ug swizzle), v2 single 8KB buffer (quad swizzle; safe:
// each wave overwrites only its own quarter after its own GEMV read).
// red[2][4][8] parity + ONE barrier/step; finish+publish by wave 0.
// ---------------------------------------------------------------------------
__global__ __launch_bounds__(256, 1) void rnn_v11(const float* __restrict__ W,
                                                  const float* __restrict__ xwg,
                                                  const float* __restrict__ b_h,
                                                  unsigned long long* __restrict__ vtag) {
    const int b = blockIdx.x;
    const int tid = threadIdx.x;
    const int gbase = b * COLS;
    const int lane = tid & 63;
    const int wid = tid >> 6;
    const int sl = lane >> 3;
    const int col = lane & 7;
    const int seg = wid * 8 + sl;

    __shared__ unsigned short Wfb[16384];   // 32 KiB bf16 W slice (v6 layout)
    __shared__ float v2[2048];              // 8 KiB, quad-swizzled, per-wave quarters
    __shared__ float xl[SEQ * COLS];        // 8 KiB
    __shared__ float red[2][4][COLS];

    // ---- stage W_hh slice as bf16 (v6 verbatim; once)
    for (int rr = 0; rr < 8; ++rr) {
        const int r = rr * 256 + tid;
        const float4 w0 = *reinterpret_cast<const float4*>(&W[(size_t)r * HID + gbase]);
        const float4 w1 = *reinterpret_cast<const float4*>(&W[(size_t)r * HID + gbase + 4]);
        const int i = (r >> 3) & 7, sg = r >> 6, e = r & 7;
        const float wv[8] = {w0.x, w0.y, w0.z, w0.w, w1.x, w1.y, w1.z, w1.w};
        #pragma unroll
        for (int c = 0; c < 8; ++c) {
            const int ug = (i * 256 + sg * 8 + c) ^ (sg & 7);
            Wfb[ug * 8 + e] = (unsigned short)f2bf(wv[c]);
        }
    }
    // ---- stage xl strip (once)
    for (int ii = 0; ii < 8; ++ii) {
        const int idx = ii * 256 + tid;
        xl[idx] = xwg[(size_t)(idx >> 3) * HID + gbase + (idx & 7)];
    }
    const float bias = (tid < COLS) ? b_h[gbase + tid] : 0.0f;
    for (int i = tid; i < 2048; i += 256) v2[i] = 0.0f;   // v_0 = 0
    __syncthreads();

    // staging addresses: thread tid -> rows tid*8..+8 = quads 2tid, 2tid+1
    const int qL0 = (2 * tid) & 127;
    const int qs = (qL0 >> 4) & 7;
    const int qt = tid >> 6;                 // == wid (own wave's quarter)
    float* const stg0 = &v2[qt * 512 + ((qL0 + 0) ^ qs) * 4];
    float* const stg1 = &v2[qt * 512 + ((qL0 + 1) ^ qs) * 4];

    for (int t = 0; t < SEQ; ++t) {
        // ---- detect: gate on word 0 of producer tid's line, then verify 1..3
        if (t > 0) {
            const unsigned long long* bb = vtag + (size_t)t * 2048 + (size_t)tid * VST;
            const unsigned tg = (unsigned)t;
            unsigned long long w0, w1, w2, w3;
            do { w0 = __hip_atomic_load(&bb[0], __ATOMIC_RELAXED,
                                        __HIP_MEMORY_SCOPE_AGENT);
            } while ((unsigned)(w0 >> 32) != tg);
            do { w1 = __hip_atomic_load(&bb[1], __ATOMIC_RELAXED,
                                        __HIP_MEMORY_SCOPE_AGENT);
            } while ((unsigned)(w1 >> 32) != tg);
            do { w2 = __hip_atomic_load(&bb[2], __ATOMIC_RELAXED,
                                        __HIP_MEMORY_SCOPE_AGENT);
            } while ((unsigned)(w2 >> 32) != tg);
            do { w3 = __hip_atomic_load(&bb[3], __ATOMIC_RELAXED,
                                        __HIP_MEMORY_SCOPE_AGENT);
            } while ((unsigned)(w3 >> 32) != tg);
            const unsigned p0 = (unsigned)w0, p1 = (unsigned)w1;
            const unsigned p2 = (unsigned)w2, p3 = (unsigned)w3;
            *reinterpret_cast<float4*>(stg0) =
                make_float4(bflo(p0), bfhi(p0), bflo(p1), bfhi(p1));
            *reinterpret_cast<float4*>(stg1) =
                make_float4(bflo(p2), bfhi(p2), bflo(p3), bfhi(p3));
        }
        // no barrier: wave staged its own quarter; lockstep+lgkmcnt order LDS

        // ---- GEMV over own 64-row chunk (v6 verbatim)
        float acc = 0.0f;
        #pragma unroll
        for (int i = 0; i < 8; ++i) {
            const int ug = (i * 256 + seg * 8 + col) ^ (seg & 7);
            const uint4 wq = *reinterpret_cast<const uint4*>(&Wfb[ug * 8]);
            const int q0 = (sl * 16 + i * 2) ^ sl;
            const int q1 = (sl * 16 + i * 2 + 1) ^ sl;
            const float4 va = *reinterpret_cast<const float4*>(&v2[wid * 512 + q0 * 4]);
            const float4 vb = *reinterpret_cast<const float4*>(&v2[wid * 512 + q1 * 4]);
            acc += bflo(wq.x) * va.x + bfhi(wq.x) * va.y
                 + bflo(wq.y) * va.z + bfhi(wq.y) * va.w
                 + bflo(wq.z) * vb.x + bfhi(wq.z) * vb.y
                 + bflo(wq.w) * vb.z + bfhi(wq.w) * vb.w;
        }
        acc += __shfl_xor(acc, 8, 64);
        acc += __shfl_xor(acc, 16, 64);
        acc += __shfl_xor(acc, 32, 64);

        const int par = t & 1;
        if (lane < COLS) red[par][wid][lane] = acc;
        __syncthreads();   // the ONE per-step barrier

        // ---- wave-0 finish + bf16-packed tagged publish
        if (wid == 0) {
            float hv = 0.0f;
            if (lane < COLS)
                hv = tanhf(red[par][0][lane] + red[par][1][lane]
                         + red[par][2][lane] + red[par][3][lane]
                         + xl[t * COLS + lane] + bias);
            const float lo = __shfl(hv, (lane & 3) * 2, 64);
            const float hi = __shfl(hv, (lane & 3) * 2 + 1, 64);
            if (lane < 4) {
                const unsigned long long pk =
                    ((unsigned long long)(unsigned)(t + 1) << 32) |
                    (unsigned long long)(f2bf(lo) | (f2bf(hi) << 16));
                __hip_atomic_store(&vtag[(size_t)(t + 1) * 2048
                                         + (size_t)b * VST + lane],
                                   pk, __ATOMIC_RELAXED, __HIP_MEMORY_SCOPE_AGENT);
            }
        }
    }
}

// ---------------------------------------------------------------------------
// Kernel 3: out = softmax(2048 * (v @ W_ph + b_p)); v = bf16 pairs in the
// step-256 lines of vtag (stream-ordered after rnn_v11 -> plain reads).
// ---------------------------------------------------------------------------
__global__ __launch_bounds__(256) void final_v5(const unsigned long long* __restrict__ vtag,
                                                const float* __restrict__ W_ph,
                                                const float* __restrict__ b_p,
                                                float* __restrict__ out) {
    __shared__ float red[256][NCLS];
    const int tid = threadIdx.x;
    const unsigned long long* base = vtag + (size_t)SEQ * 2048;
    float acc[NCLS] = {};
    for (int k = 0; k < 8; ++k) {
        const int r = k * 256 + tid;
        const unsigned long long w = base[(size_t)(r >> 3) * VST + ((r & 7) >> 1)];
        const unsigned p = (unsigned)w;
        const float v = (r & 1) ? bfhi(p) : bflo(p);
        #pragma unroll
        for (int c = 0; c < NCLS; ++c)
            acc[c] += v * W_ph[(size_t)r * NCLS + c];
    }
    #pragma unroll
    for (int c = 0; c < NCLS; ++c) red[tid][c] = acc[c];
    __syncthreads();
    for (int sft = 128; sft > 0; sft >>= 1) {
        if (tid < sft) {
            #pragma unroll
            for (int c = 0; c < NCLS; ++c)
                red[tid][c] += red[tid + sft][c];
        }
        __syncthreads();
    }
    if (tid == 0) {
        float logits[NCLS];
        float m = -1e30f;
        #pragma unroll
        for (int c = 0; c < NCLS; ++c) {
            logits[c] = (float)HID * (red[0][c] + b_p[c]);
            m = fmaxf(m, logits[c]);
        }
        float den = 0.0f, e[NCLS];
        #pragma unroll
        for (int c = 0; c < NCLS; ++c) {
            e[c] = expf(logits[c] - m);
            den += e[c];
        }
        #pragma unroll
        for (int c = 0; c < NCLS; ++c) out[c] = e[c] / den;
    }
}

// ---------------------------------------------------------------------------
extern "C" void kernel_launch(void* const* d_in, const int* in_sizes, int n_in,
                              void* d_out, int out_size, void* d_ws, size_t ws_size,
                              hipStream_t stream) {
    const float* x    = (const float*)d_in[0];
    const float* W_hx = (const float*)d_in[1];
    const float* W_hh = (const float*)d_in[2];
    const float* W_ph = (const float*)d_in[3];
    const float* b_h  = (const float*)d_in[4];
    const float* b_p  = (const float*)d_in[5];
    float* out = (float*)d_out;

    float* xw               = (float*)d_ws;                                  // 2 MB
    unsigned long long* vtag = (unsigned long long*)(xw + (size_t)SEQ * HID); // 257*2048 u64 = 4.2 MB

    // step-indexed tag/value buffer must start clean every launch (in-graph,
    // so every replay re-clears -> no cross-call state, no coasting)
    hipMemsetAsync(vtag, 0, (size_t)(SEQ + 1) * 2048 * sizeof(unsigned long long),
                   stream);

    // 1) xw = x @ W_hx
    dim3 g1(HID / 64, SEQ / 32);
    xw_gemm3<<<g1, 256, 0, stream>>>(x, W_hx, xw);

    // 2) recurrent steps (cooperative for co-residency; dataflow sync)
    {
        const float* whh_a = W_hh;
        const float* xw_a  = xw;
        const float* bh_a  = b_h;
        unsigned long long* vt_a = vtag;
        void* args[] = {(void*)&whh_a, (void*)&xw_a, (void*)&bh_a, (void*)&vt_a};
        hipLaunchCooperativeKernel((const void*)rnn_v11, dim3(NBLK), dim3(256),
                                   args, 0, stream);
    }

    // 3) projection + softmax
    final_v5<<<1, 256, 0, stream>>>(vtag, W_ph, b_p, out);
}